// Round 2
// baseline (12.061 us; speedup 1.0000x reference)
//
#include <hip/hip_runtime.h>

// 2-level inverse DWT (db4, periodic/circulant), fused into one kernel.
//
// Level 1: a=coeff0[4,2048,8], d=coeff1[4,2048,8], n=4096 -> res1[4,4096,8]
// Level 2: a=res1[4,4096,8],   d=coeff2[4,4096,8], n=8192 -> out [4,8192,8]
//
// out[k,c] = sum_{jj=0..3, j=p+2jj, p=k&1}
//              a[(k-j)/2 mod n/2, c]*LO[j] + d[(k-j)/2 mod n/2, c]*HI[j]
//
// Each block: batch b = blockIdx.y, output rows [k0, k0+KT).
// Phase 1 recomputes the NR1 = KT/2+3 level-1 rows this tile needs into LDS.
// Phase-2's coeff2 loads are HOISTED ABOVE the barrier (they don't depend on
// LDS) so both memory-latency phases overlap — single dependent load phase.

#define KT  128            // output rows per block (= blockDim.x)
#define NR1 (KT / 2 + 3)   // level-1 rows needed per tile = 67

// db4 decomposition filters (compile-time: fold into literals)
__device__ constexpr float LOF[8] = {
    -0.010597401785069032f,  0.0328830116668852f,   0.030841381835560763f,
    -0.18703481171909309f,  -0.027983769416859854f, 0.6308807679298589f,
     0.7148465705529157f,    0.23037781330889653f};
__device__ constexpr float HIF[8] = {
    -0.23037781330889653f,   0.7148465705529157f,  -0.6308807679298589f,
    -0.027983769416859854f,  0.18703481171909309f,  0.030841381835560763f,
    -0.0328830116668852f,   -0.010597401785069032f};

__device__ __forceinline__ void fma4(float4& acc, const float4 v, const float s) {
    acc.x = fmaf(v.x, s, acc.x);
    acc.y = fmaf(v.y, s, acc.y);
    acc.z = fmaf(v.z, s, acc.z);
    acc.w = fmaf(v.w, s, acc.w);
}

__global__ __launch_bounds__(KT) void idwt2_fused(
    const float* __restrict__ c0,   // [4,2048,8]
    const float* __restrict__ c1,   // [4,2048,8]
    const float* __restrict__ c2,   // [4,4096,8]
    float* __restrict__ out)        // [4,8192,8]
{
    __shared__ float res1[NR1][8];

    const int b  = blockIdx.y;
    const int k0 = blockIdx.x * KT;
    const int t  = threadIdx.x;

    const float* c0b  = c0  + b * 2048 * 8;
    const float* c1b  = c1  + b * 2048 * 8;
    const float* c2b  = c2  + b * 4096 * 8;
    float*       outb = out + b * 8192 * 8;

    // first level-1 row needed by this tile: (k0/2 - 3) mod 4096
    const int ibase = ((k0 + 8192 - 6) & 8191) >> 1;

    // ---- Prefetch phase-2's coeff2 rows (independent of LDS) ----
    const int k  = k0 + t;
    const int p  = k & 1;
    const int kb = k >> 1;                   // (k - p) / 2
    float4 d0[4], d1[4];
    int lr[4];                               // local LDS row per tap
    #pragma unroll
    for (int jj = 0; jj < 4; ++jj) {
        const int i = (kb - jj) & 4095;      // level-1 / coeff2 row index
        lr[jj] = (i - ibase) & 4095;         // local LDS row, in [0, NR1)
        const float4* D = reinterpret_cast<const float4*>(c2b + i * 8);
        d0[jj] = D[0];
        d1[jj] = D[1];
    }

    // ---- Phase 1: level-1 rows [ibase, ibase+NR1) mod 4096 -> LDS ----
    if (t < NR1) {
        const int i  = (ibase + t) & 4095;   // level-1 output row index
        const int q  = i & 1;
        const int mb = i >> 1;               // (i - q) / 2, in [0,2048)
        float4 aL = {0.f, 0.f, 0.f, 0.f}, aH = {0.f, 0.f, 0.f, 0.f};
        #pragma unroll
        for (int jj = 0; jj < 4; ++jj) {
            const int   m = (mb - jj) & 2047;
            const float h = q ? LOF[2 * jj + 1] : LOF[2 * jj];
            const float g = q ? HIF[2 * jj + 1] : HIF[2 * jj];
            const float4* A = reinterpret_cast<const float4*>(c0b + m * 8);
            const float4* D = reinterpret_cast<const float4*>(c1b + m * 8);
            const float4 a0 = A[0], a1 = A[1];
            const float4 e0 = D[0], e1 = D[1];
            fma4(aL, a0, h); fma4(aH, a1, h);
            fma4(aL, e0, g); fma4(aH, e1, g);
        }
        *reinterpret_cast<float4*>(&res1[t][0]) = aL;
        *reinterpret_cast<float4*>(&res1[t][4]) = aH;
    }
    __syncthreads();

    // ---- Phase 2: output rows [k0, k0+KT) from LDS + prefetched regs ----
    float4 aL = {0.f, 0.f, 0.f, 0.f}, aH = {0.f, 0.f, 0.f, 0.f};
    #pragma unroll
    for (int jj = 0; jj < 4; ++jj) {
        const float h = p ? LOF[2 * jj + 1] : LOF[2 * jj];
        const float g = p ? HIF[2 * jj + 1] : HIF[2 * jj];
        const float4 a0 = *reinterpret_cast<const float4*>(&res1[lr[jj]][0]);
        const float4 a1 = *reinterpret_cast<const float4*>(&res1[lr[jj]][4]);
        fma4(aL, a0, h);     fma4(aH, a1, h);
        fma4(aL, d0[jj], g); fma4(aH, d1[jj], g);
    }
    float4* O = reinterpret_cast<float4*>(outb + k * 8);
    O[0] = aL;
    O[1] = aH;
}

extern "C" void kernel_launch(void* const* d_in, const int* in_sizes, int n_in,
                              void* d_out, int out_size, void* d_ws, size_t ws_size,
                              hipStream_t stream) {
    const float* c0 = (const float*)d_in[0];   // coeff0 [4,2048,8]
    const float* c1 = (const float*)d_in[1];   // coeff1 [4,2048,8]
    const float* c2 = (const float*)d_in[2];   // coeff2 [4,4096,8]
    float* out = (float*)d_out;                // [4,8192,8]

    dim3 grid(8192 / KT, 4);                   // 64 x 4 = 256 blocks
    idwt2_fused<<<grid, KT, 0, stream>>>(c0, c1, c2, out);
}

// Round 3
// 9.490 us; speedup vs baseline: 1.2709x; 1.2709x over previous
//
#include <hip/hip_runtime.h>

// 2-level inverse DWT (db4, periodic/circulant), fused into one kernel.
// (Round-1 version, reverted: the round-2 coeff2 prefetch-hoist regressed
// 9.76 -> 12.06 us; kernel is launch-overhead-bound, keep the leanest body.)
//
// Level 1: a=coeff0[4,2048,8], d=coeff1[4,2048,8], n=4096 -> res1[4,4096,8]
// Level 2: a=res1[4,4096,8],   d=coeff2[4,4096,8], n=8192 -> out [4,8192,8]
//
// out[k,c] = sum_{jj=0..3, j=p+2jj, p=k&1}
//              a[(k-j)/2 mod n/2, c]*LO[j] + d[(k-j)/2 mod n/2, c]*HI[j]
//
// Each block: batch b = blockIdx.y, output rows [k0, k0+KT).
// Phase 1 recomputes the NR1 = KT/2+3 level-1 rows this tile needs into LDS
// (cheap boundary recompute beats a 2nd launch + global round trip).

#define KT  128            // output rows per block (= blockDim.x)
#define NR1 (KT / 2 + 3)   // level-1 rows needed per tile = 67

// db4 decomposition filters (compile-time: fold into literals)
__device__ constexpr float LOF[8] = {
    -0.010597401785069032f,  0.0328830116668852f,   0.030841381835560763f,
    -0.18703481171909309f,  -0.027983769416859854f, 0.6308807679298589f,
     0.7148465705529157f,    0.23037781330889653f};
__device__ constexpr float HIF[8] = {
    -0.23037781330889653f,   0.7148465705529157f,  -0.6308807679298589f,
    -0.027983769416859854f,  0.18703481171909309f,  0.030841381835560763f,
    -0.0328830116668852f,   -0.010597401785069032f};

__device__ __forceinline__ void fma4(float4& acc, const float4 v, const float s) {
    acc.x = fmaf(v.x, s, acc.x);
    acc.y = fmaf(v.y, s, acc.y);
    acc.z = fmaf(v.z, s, acc.z);
    acc.w = fmaf(v.w, s, acc.w);
}

__global__ __launch_bounds__(KT) void idwt2_fused(
    const float* __restrict__ c0,   // [4,2048,8]
    const float* __restrict__ c1,   // [4,2048,8]
    const float* __restrict__ c2,   // [4,4096,8]
    float* __restrict__ out)        // [4,8192,8]
{
    __shared__ float res1[NR1][8];

    const int b  = blockIdx.y;
    const int k0 = blockIdx.x * KT;
    const int t  = threadIdx.x;

    const float* c0b  = c0  + b * 2048 * 8;
    const float* c1b  = c1  + b * 2048 * 8;
    const float* c2b  = c2  + b * 4096 * 8;
    float*       outb = out + b * 8192 * 8;

    // first level-1 row needed by this tile: (k0/2 - 3) mod 4096
    const int ibase = ((k0 + 8192 - 6) & 8191) >> 1;

    // ---- Phase 1: level-1 rows [ibase, ibase+NR1) mod 4096 -> LDS ----
    if (t < NR1) {
        const int i  = (ibase + t) & 4095;   // level-1 output row index
        const int p  = i & 1;
        const int mb = i >> 1;               // (i - p) / 2, in [0,2048)
        float4 aL = {0.f, 0.f, 0.f, 0.f}, aH = {0.f, 0.f, 0.f, 0.f};
        #pragma unroll
        for (int jj = 0; jj < 4; ++jj) {
            const int   m = (mb - jj) & 2047;
            const float h = p ? LOF[2 * jj + 1] : LOF[2 * jj];
            const float g = p ? HIF[2 * jj + 1] : HIF[2 * jj];
            const float4* A = reinterpret_cast<const float4*>(c0b + m * 8);
            const float4* D = reinterpret_cast<const float4*>(c1b + m * 8);
            const float4 a0 = A[0], a1 = A[1];
            const float4 d0 = D[0], d1 = D[1];
            fma4(aL, a0, h); fma4(aH, a1, h);
            fma4(aL, d0, g); fma4(aH, d1, g);
        }
        *reinterpret_cast<float4*>(&res1[t][0]) = aL;
        *reinterpret_cast<float4*>(&res1[t][4]) = aH;
    }
    __syncthreads();

    // ---- Phase 2: output rows [k0, k0+KT) ----
    const int k  = k0 + t;
    const int p  = k & 1;
    const int kb = k >> 1;                   // (k - p) / 2
    float4 aL = {0.f, 0.f, 0.f, 0.f}, aH = {0.f, 0.f, 0.f, 0.f};
    #pragma unroll
    for (int jj = 0; jj < 4; ++jj) {
        const int   i = (kb - jj) & 4095;    // level-1 / coeff2 row index
        const int   r = (i - ibase) & 4095;  // local LDS row, in [0, NR1)
        const float h = p ? LOF[2 * jj + 1] : LOF[2 * jj];
        const float g = p ? HIF[2 * jj + 1] : HIF[2 * jj];
        const float4 a0 = *reinterpret_cast<const float4*>(&res1[r][0]);
        const float4 a1 = *reinterpret_cast<const float4*>(&res1[r][4]);
        const float4* D = reinterpret_cast<const float4*>(c2b + i * 8);
        const float4 d0 = D[0], d1 = D[1];
        fma4(aL, a0, h); fma4(aH, a1, h);
        fma4(aL, d0, g); fma4(aH, d1, g);
    }
    float4* O = reinterpret_cast<float4*>(outb + k * 8);
    O[0] = aL;
    O[1] = aH;
}

extern "C" void kernel_launch(void* const* d_in, const int* in_sizes, int n_in,
                              void* d_out, int out_size, void* d_ws, size_t ws_size,
                              hipStream_t stream) {
    const float* c0 = (const float*)d_in[0];   // coeff0 [4,2048,8]
    const float* c1 = (const float*)d_in[1];   // coeff1 [4,2048,8]
    const float* c2 = (const float*)d_in[2];   // coeff2 [4,4096,8]
    float* out = (float*)d_out;                // [4,8192,8]

    dim3 grid(8192 / KT, 4);                   // 64 x 4 = 256 blocks
    idwt2_fused<<<grid, KT, 0, stream>>>(c0, c1, c2, out);
}